// Round 1
// 115.353 us; speedup vs baseline: 1.0376x; 1.0376x over previous
//
#include <hip/hip_runtime.h>

#define N_SAMPLES 4096
#define DIM 2048
#define NUM_CLASSES 128
#define MARGIN 0.5f

// ---------------- ws layout (byte offsets) ----------------
// cnt   : C ints        @ 0
// meanR : C*D floats    @ 1024
// meanT : C*D floats    @ 1024 + C*D*4
//
// History:
//   R3  = 118.8 us (4-deep unroll mean, 256-block loss). Best so far.
//   R5  (nontemporal + 8-deep unroll): +13 us — regression (likely the nt
//        bypass, not the unroll; they were bundled).
//   R6  (loss algebraic refactor): +7 us — noise/regression; reverted.
//   R8  (this): (a) mean gather = explicit 8-deep register double-buffer
//        (prefetch next 8 rows before accumulating current 8) — keeps 8
//        loads in flight instead of draining vmcnt per 4-row group.
//        (b) loss = one 4x4 tile per block, 4 waves split D, LDS combine
//        before the nonlinearity — 4096 waves (4/SIMD) instead of 1024.

// Kernel 1: per-class means, self-contained (no pre-sort).
// grid (2, C, 2), block 256. Each block scans targets (16 KB, L2-hot),
// compacts its class's rows into LDS, then sums float4 columns with an
// 8-deep software pipeline. Inputs read exactly once across the grid.
__global__ __launch_bounds__(256) void mean_kernel(
        const float* __restrict__ x1,
        const float* __restrict__ x2,
        const int* __restrict__ targets,
        int* __restrict__ cnt,
        float* __restrict__ meanR,
        float* __restrict__ meanT,
        float* __restrict__ d_out, int out_size) {
    __shared__ int s_rows[N_SAMPLES];
    __shared__ int s_n;
    const int tid = threadIdx.x;
    const int c = blockIdx.y;
    const float* __restrict__ x = (blockIdx.z == 0) ? x1 : x2;
    float* __restrict__ mean    = (blockIdx.z == 0) ? meanR : meanT;

    if (tid == 0) s_n = 0;
    if (blockIdx.x == 0 && blockIdx.y == 0 && blockIdx.z == 0) {
        for (int i = tid; i < out_size; i += 256) d_out[i] = 0.0f;  // loss runs after us
    }
    __syncthreads();

    // compact rows of class c (order irrelevant)
    const int4* __restrict__ t4 = (const int4*)targets;
    for (int i = tid; i < N_SAMPLES / 4; i += 256) {
        const int4 v = t4[i];
        const int base = i * 4;
        if (v.x == c) s_rows[atomicAdd(&s_n, 1)] = base;
        if (v.y == c) s_rows[atomicAdd(&s_n, 1)] = base + 1;
        if (v.z == c) s_rows[atomicAdd(&s_n, 1)] = base + 2;
        if (v.w == c) s_rows[atomicAdd(&s_n, 1)] = base + 3;
    }
    __syncthreads();
    const int n = s_n;

    const int col = blockIdx.x * 256 + tid;          // float4 index in [0,512)
    const float4* __restrict__ xs = (const float4*)x;
    float ax = 0.0f, ay = 0.0f, az = 0.0f, aw = 0.0f;

    int k = 0;
    const int body = n & ~7;                          // multiple of 8
    if (body >= 8) {
        // prologue: group 0 in flight
        int r0 = s_rows[0], r1 = s_rows[1], r2 = s_rows[2], r3 = s_rows[3];
        int r4 = s_rows[4], r5 = s_rows[5], r6 = s_rows[6], r7 = s_rows[7];
        float4 v0 = xs[(size_t)r0 * (DIM / 4) + col];
        float4 v1 = xs[(size_t)r1 * (DIM / 4) + col];
        float4 v2 = xs[(size_t)r2 * (DIM / 4) + col];
        float4 v3 = xs[(size_t)r3 * (DIM / 4) + col];
        float4 v4 = xs[(size_t)r4 * (DIM / 4) + col];
        float4 v5 = xs[(size_t)r5 * (DIM / 4) + col];
        float4 v6 = xs[(size_t)r6 * (DIM / 4) + col];
        float4 v7 = xs[(size_t)r7 * (DIM / 4) + col];

#pragma unroll 1
        for (k = 8; k + 8 <= body; k += 8) {
            // issue next group's loads BEFORE consuming current group
            const int q0 = s_rows[k + 0], q1 = s_rows[k + 1];
            const int q2 = s_rows[k + 2], q3 = s_rows[k + 3];
            const int q4 = s_rows[k + 4], q5 = s_rows[k + 5];
            const int q6 = s_rows[k + 6], q7 = s_rows[k + 7];
            const float4 w0 = xs[(size_t)q0 * (DIM / 4) + col];
            const float4 w1 = xs[(size_t)q1 * (DIM / 4) + col];
            const float4 w2 = xs[(size_t)q2 * (DIM / 4) + col];
            const float4 w3 = xs[(size_t)q3 * (DIM / 4) + col];
            const float4 w4 = xs[(size_t)q4 * (DIM / 4) + col];
            const float4 w5 = xs[(size_t)q5 * (DIM / 4) + col];
            const float4 w6 = xs[(size_t)q6 * (DIM / 4) + col];
            const float4 w7 = xs[(size_t)q7 * (DIM / 4) + col];

            ax += ((v0.x + v1.x) + (v2.x + v3.x)) + ((v4.x + v5.x) + (v6.x + v7.x));
            ay += ((v0.y + v1.y) + (v2.y + v3.y)) + ((v4.y + v5.y) + (v6.y + v7.y));
            az += ((v0.z + v1.z) + (v2.z + v3.z)) + ((v4.z + v5.z) + (v6.z + v7.z));
            aw += ((v0.w + v1.w) + (v2.w + v3.w)) + ((v4.w + v5.w) + (v6.w + v7.w));

            v0 = w0; v1 = w1; v2 = w2; v3 = w3;
            v4 = w4; v5 = w5; v6 = w6; v7 = w7;
        }
        // epilogue: last full group
        ax += ((v0.x + v1.x) + (v2.x + v3.x)) + ((v4.x + v5.x) + (v6.x + v7.x));
        ay += ((v0.y + v1.y) + (v2.y + v3.y)) + ((v4.y + v5.y) + (v6.y + v7.y));
        az += ((v0.z + v1.z) + (v2.z + v3.z)) + ((v4.z + v5.z) + (v6.z + v7.z));
        aw += ((v0.w + v1.w) + (v2.w + v3.w)) + ((v4.w + v5.w) + (v6.w + v7.w));
        k = body;
    }
    for (; k < n; ++k) {
        const int r = s_rows[k];
        const float4 v = xs[(size_t)r * (DIM / 4) + col];
        ax += v.x; ay += v.y; az += v.z; aw += v.w;
    }

    const float inv = 1.0f / (float)((n > 0) ? n : 1);
    float4 m; m.x = ax * inv; m.y = ay * inv; m.z = az * inv; m.w = aw * inv;
    ((float4*)mean)[(size_t)c * (DIM / 4) + col] = m;

    if (blockIdx.x == 0 && blockIdx.z == 0 && tid == 0) cnt[c] = n;
}

__device__ __forceinline__ void accum_sq(float& acc, const float4& a, const float4& c) {
    float d;
    d = a.x - c.x; acc = fmaf(d, d, acc);
    d = a.y - c.y; acc = fmaf(d, d, acc);
    d = a.z - c.z; acc = fmaf(d, d, acc);
    d = a.w - c.w; acc = fmaf(d, d, acc);
}

__device__ __forceinline__ float wave_sum64(float v) {
#pragma unroll
    for (int m = 32; m >= 1; m >>= 1) v += __shfl_xor(v, m, 64);
    return v;
}

// Kernel 2: class-pair distances + contrastive terms.
// One BLOCK per 4a x 4b tile (1024 blocks); the block's 4 waves each cover
// a quarter of D (128 float4 = 2 iters of 64). Partial squared distances
// are combined in LDS BEFORE the sqrt/relu nonlinearity. 4096 waves total
// (4/SIMD) vs the old 1024 (1/SIMD) — same L2 traffic, 4x the latency
// hiding. Means (2 MB) are L2-resident.
__global__ __launch_bounds__(256) void loss_kernel(
        const float* __restrict__ meanR,
        const float* __restrict__ meanT,
        const int* __restrict__ cnt,
        float* __restrict__ d_out) {
    const int tile = blockIdx.x;         // 0..1023
    const int a0 = (tile >> 5) * 4;      // a-tile: 4 classes
    const int b0 = (tile & 31) * 4;      // b-tile: 4 classes
    const int wave = threadIdx.x >> 6;   // 0..3 -> quarter of D
    const int lane = threadIdx.x & 63;

    float acc1[4][4], acc2[4][4];
#pragma unroll
    for (int i = 0; i < 4; ++i)
#pragma unroll
        for (int j = 0; j < 4; ++j) { acc1[i][j] = 0.0f; acc2[i][j] = 0.0f; }

#pragma unroll
    for (int it = 0; it < 2; ++it) {
        const int d = wave * 128 + it * 64 + lane;   // float4 index within a row
        float4 ra[4], ta[4];
#pragma unroll
        for (int i = 0; i < 4; ++i) {
            ra[i] = ((const float4*)(meanR + (size_t)(a0 + i) * DIM))[d];
            ta[i] = ((const float4*)(meanT + (size_t)(a0 + i) * DIM))[d];
        }
#pragma unroll
        for (int j = 0; j < 4; ++j) {
            const int b = b0 + j;
            const float4 rb = ((const float4*)(meanR + (size_t)b * DIM))[d];
            const float4 tb = ((const float4*)(meanT + (size_t)b * DIM))[d];
            float4 cb;
            cb.x = 0.5f * (rb.x + tb.x);
            cb.y = 0.5f * (rb.y + tb.y);
            cb.z = 0.5f * (rb.z + tb.z);
            cb.w = 0.5f * (rb.w + tb.w);
#pragma unroll
            for (int i = 0; i < 4; ++i) {
                accum_sq(acc1[i][j], ra[i], cb);
                accum_sq(acc2[i][j], ta[i], cb);
            }
        }
    }

#pragma unroll
    for (int i = 0; i < 4; ++i)
#pragma unroll
        for (int j = 0; j < 4; ++j) {
            acc1[i][j] = wave_sum64(acc1[i][j]);
            acc2[i][j] = wave_sum64(acc2[i][j]);
        }

    // combine the 4 per-wave D-partials before the nonlinearity
    __shared__ float s1[4][16], s2[4][16];
    if (lane == 0) {
#pragma unroll
        for (int i = 0; i < 4; ++i)
#pragma unroll
            for (int j = 0; j < 4; ++j) {
                s1[wave][i * 4 + j] = acc1[i][j];
                s2[wave][i * 4 + j] = acc2[i][j];
            }
    }
    __syncthreads();

    if (threadIdx.x < 64) {
        float total = 0.0f;
        if (threadIdx.x < 16) {
            const int idx = threadIdx.x;
            const int i = idx >> 2, j = idx & 3;
            const int a = a0 + i, b = b0 + j;
            const float sqa1 = (s1[0][idx] + s1[1][idx]) + (s1[2][idx] + s1[3][idx]);
            const float sqa2 = (s2[0][idx] + s2[1][idx]) + (s2[2][idx] + s2[3][idx]);
            const float invN2 = 1.0f / ((float)N_SAMPLES * (float)N_SAMPLES);
            const float w = (float)cnt[a] * (float)cnt[b] * invN2;
            const float sq1 = fmaxf(sqa1, 1e-12f);
            const float sq2 = fmaxf(sqa2, 1e-12f);
            float t1, t2;
            if (a == b) {
                t1 = sq1;                 // label==1: d2^2 == clamped sq
                t2 = sq2;
            } else {
                const float dd1 = sqrtf(sqrtf(sq1) + 1e-10f);
                const float dd2 = sqrtf(sqrtf(sq2) + 1e-10f);
                const float r1 = fmaxf(MARGIN - dd1, 0.0f);
                const float r2 = fmaxf(MARGIN - dd2, 0.0f);
                t1 = r1 * r1;
                t2 = r2 * r2;
            }
            total = w * (t1 + t2);
        }
        total = wave_sum64(total);       // lanes 16..63 contribute 0
        if (threadIdx.x == 0) atomicAdd(d_out, total);
    }
}

extern "C" void kernel_launch(void* const* d_in, const int* in_sizes, int n_in,
                              void* d_out, int out_size, void* d_ws, size_t ws_size,
                              hipStream_t stream) {
    const float* modal1 = (const float*)d_in[0];
    const float* modal2 = (const float*)d_in[1];
    const int* targets  = (const int*)d_in[2];
    float* out = (float*)d_out;

    char* ws = (char*)d_ws;
    int*   cnt   = (int*)(ws + 0);
    float* meanR = (float*)(ws + 1024);
    float* meanT = (float*)(ws + 1024 + (size_t)NUM_CLASSES * DIM * 4);

    // 1. per-class means (self-gathering; also zeroes d_out, publishes cnt)
    dim3 gridB(2, NUM_CLASSES, 2);
    mean_kernel<<<gridB, 256, 0, stream>>>(modal1, modal2, targets, cnt,
                                           meanR, meanT, out, out_size);

    // 2. class-pair losses -> scalar (one 4x4 tile per block, 4 waves split D)
    loss_kernel<<<NUM_CLASSES / 4 * NUM_CLASSES / 4, 256, 0, stream>>>(
        meanR, meanT, cnt, out);
}